// Round 5
// baseline (1861.806 us; speedup 1.0000x reference)
//
#include <hip/hip_runtime.h>
#include <hip/hip_fp16.h>

typedef unsigned int u32;
typedef _Float16 half2_t __attribute__((ext_vector_type(2)));
typedef u32 u32x4 __attribute__((ext_vector_type(4)));

// ---- constants (B=64, T=1024, D=H=256) ----
#define NB   64
#define NT   1024
#define NH   256
#define G3   768          // 3*H
#define NK2  128          // K/2 packed f16 pairs
#define WPACK_ELEMS 98304 // NK2 * G3 per direction
#define KSPLIT 4
#define KPER   32         // k2 values per thread (NK2 / KSPLIT)

// Forbid rematerialization: value must live in a VGPR from here on.
#define PIN(x) asm volatile("" : "+v"(x))

static __device__ __forceinline__ float fdot2f(u32 a, u32 b, float c) {
#if __has_builtin(__builtin_amdgcn_fdot2)
    return __builtin_amdgcn_fdot2(__builtin_bit_cast(half2_t, a),
                                  __builtin_bit_cast(half2_t, b), c, false);
#else
    half2_t av = __builtin_bit_cast(half2_t, a);
    half2_t bv = __builtin_bit_cast(half2_t, b);
    c = fmaf((float)av[0], (float)bv[0], c);
    c = fmaf((float)av[1], (float)bv[1], c);
    return c;
#endif
}

static __device__ __forceinline__ u32 packh2(float lo, float hi) {
    half2_t v;
    v[0] = (_Float16)lo;
    v[1] = (_Float16)hi;
    return __builtin_bit_cast(u32, v);
}

static __device__ __forceinline__ float sigmoidf_fast(float x) {
    return 1.0f / (1.0f + __expf(-x));
}
static __device__ __forceinline__ float tanhf_fast(float x) {
    return 2.0f / (1.0f + __expf(-2.0f * x)) - 1.0f;
}

// Pack a (768,256) fp32 weight matrix (both directions) into f16-pair stream
// layout: dst[dir][k2][g] = half2(w[g][2k2], w[g][2k2+1]), g = gate*256 + j.
__global__ void pack_w(const float* __restrict__ src_fw,
                       const float* __restrict__ src_bw,
                       u32* __restrict__ dst) {
    int id = blockIdx.x * 256 + threadIdx.x;   // [0, 2*98304)
    int dir = id >= WPACK_ELEMS;
    int r   = id - dir * WPACK_ELEMS;          // [0, 98304)
    int j    = r & 255;
    int q    = r >> 8;                         // [0, 384)
    int gate = q % 3;
    int k2   = q / 3;
    const float* src = dir ? src_bw : src_fw;
    int g = gate * 256 + j;
    float lo = src[g * 256 + 2 * k2];
    float hi = src[g * 256 + 2 * k2 + 1];
    dst[dir * WPACK_ELEMS + k2 * G3 + g] = packh2(lo, hi);
}

// gates_x GEMM: gx[dir][m][g] = sum_k x[m][k]*w_ih[dir][g][k] + b_ih[dir][g]
__global__ __launch_bounds__(256) void gemm_gx(
        const float* __restrict__ x, const u32* __restrict__ wihp,
        const float* __restrict__ bih_fw, const float* __restrict__ bih_bw,
        _Float16* __restrict__ gx) {
    int dir = blockIdx.y;
    int m0  = blockIdx.x * 16;
    int j   = threadIdx.x;

    __shared__ u32 xs[16][NK2];
    #pragma unroll
    for (int rep = 0; rep < 8; ++rep) {
        int lin = rep * 256 + j;       // [0, 2048)
        int mi  = lin >> 7;
        int k2  = lin & 127;
        const float* xr = x + (size_t)(m0 + mi) * 256 + 2 * k2;
        xs[mi][k2] = packh2(xr[0], xr[1]);
    }
    __syncthreads();

    const u32* wp = wihp + dir * WPACK_ELEMS;
    const float* bih = dir ? bih_bw : bih_fw;

    float accr[16], accz[16], accn[16];
    #pragma unroll
    for (int mi = 0; mi < 16; ++mi) { accr[mi] = 0.f; accz[mi] = 0.f; accn[mi] = 0.f; }

    #pragma unroll 2
    for (int k2 = 0; k2 < NK2; ++k2) {
        u32 wr = wp[k2 * G3 + j];
        u32 wz = wp[k2 * G3 + 256 + j];
        u32 wn = wp[k2 * G3 + 512 + j];
        #pragma unroll
        for (int mi = 0; mi < 16; ++mi) {
            u32 xv = xs[mi][k2];
            accr[mi] = fdot2f(xv, wr, accr[mi]);
            accz[mi] = fdot2f(xv, wz, accz[mi]);
            accn[mi] = fdot2f(xv, wn, accn[mi]);
        }
    }

    float br = bih[j], bz = bih[256 + j], bn = bih[512 + j];
    _Float16* gxd = gx + (size_t)dir * 65536 * G3;
    #pragma unroll
    for (int mi = 0; mi < 16; ++mi) {
        size_t row = (size_t)(m0 + mi) * G3;
        gxd[row + j]       = (_Float16)(accr[mi] + br);
        gxd[row + 256 + j] = (_Float16)(accz[mi] + bz);
        gxd[row + 512 + j] = (_Float16)(accn[mi] + bn);
    }
}

// Recurrence: one block per (batch, direction) chain, 1024 threads (16 waves).
// Thread (q = tid>>8, j = tid&255) holds w_hh rows {j, 256+j, 512+j} for
// k2 in [32q, 32q+32) -> 96 weight VGPRs per thread.
// amdgpu_waves_per_eu(4,4) clamps the allocator's occupancy TARGET to 4
// waves/EU (budget exactly 128 VGPRs); PIN() forbids rematerializing the
// weight loads inside the loop. (Rounds 2-4 failure mode: allocator targeted
// 64 regs for 8-wave occupancy and sank the weight loads into the loop.)
__global__ __launch_bounds__(1024)
__attribute__((amdgpu_waves_per_eu(4, 4)))
void gru_rec(
        const _Float16* __restrict__ gx, const u32* __restrict__ whhp,
        const float* __restrict__ bhh_fw, const float* __restrict__ bhh_bw,
        float* __restrict__ out) {
    int b   = blockIdx.x;
    int dir = blockIdx.y;
    int tid = threadIdx.x;
    int j   = tid & 255;
    int q   = tid >> 8;          // wave-uniform (waves 0..3 -> q=0, etc.)

    __shared__ alignas(16) u32 hl[2][NK2];   // double-buffered h as packed f16 pairs
    __shared__ float psum[KSPLIT - 1][G3];   // partials from q=1..3 only (9 KB)

    const u32* wp = whhp + dir * WPACK_ELEMS;

    u32 wr[KPER], wz[KPER], wn[KPER];
    #pragma unroll
    for (int k = 0; k < KPER; ++k) {
        int k2 = q * KPER + k;
        wr[k] = wp[k2 * G3 + j];       PIN(wr[k]);
        wz[k] = wp[k2 * G3 + 256 + j]; PIN(wz[k]);
        wn[k] = wp[k2 * G3 + 512 + j]; PIN(wn[k]);
    }

    const float* bhh = dir ? bhh_bw : bhh_fw;
    float bhr = bhh[j], bhz = bhh[256 + j], bhn = bhh[512 + j];

    const _Float16* gxp = gx + ((size_t)dir * NB + b) * NT * G3;
    float* outp = out + (size_t)b * NT * 512 + dir * 256 + j;

    float h = 0.0f;
    if (tid < 256) ((_Float16*)hl)[tid] = (_Float16)0.0f;   // zero buffer 0
    __syncthreads();

    const int tstep = dir ? -1 : 1;
    int t = dir ? (NT - 1) : 0;

    // prefetch gx for the first step (q==0 threads only)
    _Float16 ngr = (_Float16)0.f, ngz = (_Float16)0.f, ngn = (_Float16)0.f;
    if (q == 0) {
        const _Float16* gxt = gxp + (size_t)t * G3;
        ngr = gxt[j]; ngz = gxt[256 + j]; ngn = gxt[512 + j];
    }

    int cur = 0;
    for (int tt = 0; tt < NT; ++tt, t += tstep) {
        // consume prefetched gx; issue next step's loads (latency hides under dots)
        float gxr = (float)ngr, gxz = (float)ngz, gxn = (float)ngn;
        if (q == 0 && tt + 1 < NT) {
            const _Float16* gxt = gxp + (size_t)(t + tstep) * G3;
            ngr = gxt[j]; ngz = gxt[256 + j]; ngn = gxt[512 + j];
        }

        // partial dots over this thread's 32 k2 values
        float ar = 0.f, az = 0.f, an = 0.f;
        const u32x4* hp = (const u32x4*)hl[cur] + q * 8;
        #pragma unroll
        for (int k4 = 0; k4 < 8; ++k4) {
            u32x4 hv = hp[k4];   // wave-uniform address -> LDS broadcast
            #pragma unroll
            for (int e = 0; e < 4; ++e) {
                int k = k4 * 4 + e;
                ar = fdot2f(hv[e], wr[k], ar);
                az = fdot2f(hv[e], wz[k], az);
                an = fdot2f(hv[e], wn[k], an);
            }
        }
        if (q != 0) {
            psum[q - 1][j]       = ar;
            psum[q - 1][256 + j] = az;
            psum[q - 1][512 + j] = an;
        }

        asm volatile("s_waitcnt lgkmcnt(0)" ::: "memory");
        __builtin_amdgcn_s_barrier();
        asm volatile("" ::: "memory");

        if (q == 0) {
            float arT = ar + psum[0][j]       + psum[1][j]       + psum[2][j];
            float azT = az + psum[0][256 + j] + psum[1][256 + j] + psum[2][256 + j];
            float anT = an + psum[0][512 + j] + psum[1][512 + j] + psum[2][512 + j];

            float r = sigmoidf_fast(gxr + arT + bhr);
            float z = sigmoidf_fast(gxz + azT + bhz);
            float n = tanhf_fast(gxn + r * (anT + bhn));
            h = z * h + (1.0f - z) * n;

            ((_Float16*)hl[cur ^ 1])[j] = (_Float16)h;
            outp[(size_t)t * 512] = h;
        }

        asm volatile("s_waitcnt lgkmcnt(0)" ::: "memory");
        __builtin_amdgcn_s_barrier();
        asm volatile("" ::: "memory");
        cur ^= 1;
    }

    if (q == 0) {
        float* hout = out + (size_t)NB * NT * 512 + dir * (NB * NH);
        hout[b * NH + j] = h;
    }
}

extern "C" void kernel_launch(void* const* d_in, const int* in_sizes, int n_in,
                              void* d_out, int out_size, void* d_ws, size_t ws_size,
                              hipStream_t stream) {
    const float* x      = (const float*)d_in[0];
    const float* wih_fw = (const float*)d_in[1];
    const float* whh_fw = (const float*)d_in[2];
    const float* bih_fw = (const float*)d_in[3];
    const float* bhh_fw = (const float*)d_in[4];
    const float* wih_bw = (const float*)d_in[5];
    const float* whh_bw = (const float*)d_in[6];
    const float* bih_bw = (const float*)d_in[7];
    const float* bhh_bw = (const float*)d_in[8];
    float* out = (float*)d_out;

    char* ws = (char*)d_ws;
    _Float16* gx = (_Float16*)ws;                      // 2*65536*768*2 = 201,326,592 B
    u32* wihp = (u32*)(ws + 201326592);                // 786,432 B
    u32* whhp = (u32*)(ws + 202113024);                // 786,432 B

    pack_w<<<768, 256, 0, stream>>>(wih_fw, wih_bw, wihp);
    pack_w<<<768, 256, 0, stream>>>(whh_fw, whh_bw, whhp);
    gemm_gx<<<dim3(4096, 2), 256, 0, stream>>>(x, wihp, bih_fw, bih_bw, gx);
    gru_rec<<<dim3(NB, 2), 1024, 0, stream>>>(gx, whhp, bhh_fw, bhh_bw, out);
}

// Round 6
// 1666.129 us; speedup vs baseline: 1.1174x; 1.1174x over previous
//
#include <hip/hip_runtime.h>
#include <hip/hip_fp16.h>

typedef unsigned int u32;
typedef _Float16 half2_t __attribute__((ext_vector_type(2)));
typedef u32 u32x4 __attribute__((ext_vector_type(4)));

// ---- constants (B=64, T=1024, D=H=256) ----
#define NB   64
#define NT   1024
#define NH   256
#define G3   768          // 3*H
#define NK2  128          // K/2 packed f16 pairs
#define WPACK_ELEMS 98304 // NK2 * G3 per direction
#define KSPLIT 4
#define KPER   32         // k2 values per thread (NK2 / KSPLIT)

// Forbid rematerialization: value must live in a VGPR from here on.
#define PIN(x) asm volatile("" : "+v"(x))

static __device__ __forceinline__ float fdot2f(u32 a, u32 b, float c) {
#if __has_builtin(__builtin_amdgcn_fdot2)
    return __builtin_amdgcn_fdot2(__builtin_bit_cast(half2_t, a),
                                  __builtin_bit_cast(half2_t, b), c, false);
#else
    half2_t av = __builtin_bit_cast(half2_t, a);
    half2_t bv = __builtin_bit_cast(half2_t, b);
    c = fmaf((float)av[0], (float)bv[0], c);
    c = fmaf((float)av[1], (float)bv[1], c);
    return c;
#endif
}

static __device__ __forceinline__ u32 packh2(float lo, float hi) {
    half2_t v;
    v[0] = (_Float16)lo;
    v[1] = (_Float16)hi;
    return __builtin_bit_cast(u32, v);
}

static __device__ __forceinline__ float sigmoidf_fast(float x) {
    return 1.0f / (1.0f + __expf(-x));
}
static __device__ __forceinline__ float tanhf_fast(float x) {
    return 2.0f / (1.0f + __expf(-2.0f * x)) - 1.0f;
}

// Pack a (768,256) fp32 weight matrix (both directions) into f16-pair stream
// layout: dst[dir][k2][g] = half2(w[g][2k2], w[g][2k2+1]), g = gate*256 + j.
__global__ void pack_w(const float* __restrict__ src_fw,
                       const float* __restrict__ src_bw,
                       u32* __restrict__ dst) {
    int id = blockIdx.x * 256 + threadIdx.x;   // [0, 2*98304)
    int dir = id >= WPACK_ELEMS;
    int r   = id - dir * WPACK_ELEMS;          // [0, 98304)
    int j    = r & 255;
    int q    = r >> 8;                         // [0, 384)
    int gate = q % 3;
    int k2   = q / 3;
    const float* src = dir ? src_bw : src_fw;
    int g = gate * 256 + j;
    float lo = src[g * 256 + 2 * k2];
    float hi = src[g * 256 + 2 * k2 + 1];
    dst[dir * WPACK_ELEMS + k2 * G3 + g] = packh2(lo, hi);
}

// gates_x GEMM: gx[dir][m][g] = sum_k x[m][k]*w_ih[dir][g][k] + b_ih[dir][g]
// Also folds the ADDITIVE recurrent biases bhh_r, bhh_z into the r/z outputs
// (bhh_n cannot be folded: it is multiplied by the r gate in the recurrence).
__global__ __launch_bounds__(256) void gemm_gx(
        const float* __restrict__ x, const u32* __restrict__ wihp,
        const float* __restrict__ bih_fw, const float* __restrict__ bih_bw,
        const float* __restrict__ bhh_fw, const float* __restrict__ bhh_bw,
        _Float16* __restrict__ gx) {
    int dir = blockIdx.y;
    int m0  = blockIdx.x * 16;
    int j   = threadIdx.x;

    __shared__ u32 xs[16][NK2];
    #pragma unroll
    for (int rep = 0; rep < 8; ++rep) {
        int lin = rep * 256 + j;       // [0, 2048)
        int mi  = lin >> 7;
        int k2  = lin & 127;
        const float* xr = x + (size_t)(m0 + mi) * 256 + 2 * k2;
        xs[mi][k2] = packh2(xr[0], xr[1]);
    }
    __syncthreads();

    const u32* wp = wihp + dir * WPACK_ELEMS;
    const float* bih = dir ? bih_bw : bih_fw;
    const float* bhh = dir ? bhh_bw : bhh_fw;

    float accr[16], accz[16], accn[16];
    #pragma unroll
    for (int mi = 0; mi < 16; ++mi) { accr[mi] = 0.f; accz[mi] = 0.f; accn[mi] = 0.f; }

    #pragma unroll 2
    for (int k2 = 0; k2 < NK2; ++k2) {
        u32 wr = wp[k2 * G3 + j];
        u32 wz = wp[k2 * G3 + 256 + j];
        u32 wn = wp[k2 * G3 + 512 + j];
        #pragma unroll
        for (int mi = 0; mi < 16; ++mi) {
            u32 xv = xs[mi][k2];
            accr[mi] = fdot2f(xv, wr, accr[mi]);
            accz[mi] = fdot2f(xv, wz, accz[mi]);
            accn[mi] = fdot2f(xv, wn, accn[mi]);
        }
    }

    float br = bih[j] + bhh[j];                // fold bhh_r
    float bz = bih[256 + j] + bhh[256 + j];    // fold bhh_z
    float bn = bih[512 + j];
    _Float16* gxd = gx + (size_t)dir * 65536 * G3;
    #pragma unroll
    for (int mi = 0; mi < 16; ++mi) {
        size_t row = (size_t)(m0 + mi) * G3;
        gxd[row + j]       = (_Float16)(accr[mi] + br);
        gxd[row + 256 + j] = (_Float16)(accz[mi] + bz);
        gxd[row + 512 + j] = (_Float16)(accn[mi] + bn);
    }
}

// Recurrence: one block per (batch, direction) chain, 1024 threads (16 waves).
// Thread (q = tid>>8, j = tid&255) holds w_hh rows {j, 256+j, 512+j} for
// k2 in [32q, 32q+32) -> 96 weight VGPRs per thread.
// OCCUPANCY CLAMP VIA LDS: the 84 KB pad makes a second 1024-thread block
// per CU impossible, so max occupancy is provably 4 waves/EU and the register
// allocator's budget is the full 128 VGPRs/wave (512/SIMD / 4 waves). Rounds
// 3-5 showed that without this the allocator targets 64 regs for 8-wave
// occupancy and spills the weight array into the loop (L2-streaming floor
// ~1.49 ms = 51.5 GB / 34.5 TB/s, measured 1.48 ms).
__global__ __launch_bounds__(1024)
__attribute__((amdgpu_waves_per_eu(4, 4)))
void gru_rec(
        const _Float16* __restrict__ gx, const u32* __restrict__ whhp,
        const float* __restrict__ bhh_fw, const float* __restrict__ bhh_bw,
        float* __restrict__ out) {
    int b   = blockIdx.x;
    int dir = blockIdx.y;
    int tid = threadIdx.x;
    int j   = tid & 255;
    int q   = tid >> 8;          // wave-uniform (waves 0..3 -> q=0, etc.)

    __shared__ alignas(16) u32 hl[2][NK2];   // double-buffered h as packed f16 pairs
    __shared__ float psum[KSPLIT - 1][G3];   // partials from q=1..3 only (9 KB)
    __shared__ char occ_pad[86016];          // 84 KB occupancy clamp (see above)
    if (gx == nullptr) occ_pad[tid] = 1;     // never taken; keeps pad allocated

    const u32* wp = whhp + dir * WPACK_ELEMS;

    u32 wr[KPER], wz[KPER], wn[KPER];
    #pragma unroll
    for (int k = 0; k < KPER; ++k) {
        int k2 = q * KPER + k;
        wr[k] = wp[k2 * G3 + j];       PIN(wr[k]);
        wz[k] = wp[k2 * G3 + 256 + j]; PIN(wz[k]);
        wn[k] = wp[k2 * G3 + 512 + j]; PIN(wn[k]);
    }

    const float* bhh = dir ? bhh_bw : bhh_fw;
    float bhn = bhh[512 + j];    // bhh_r/bhh_z were folded into gx

    const _Float16* gxp = gx + ((size_t)dir * NB + b) * NT * G3;
    float* outp = out + (size_t)b * NT * 512 + dir * 256 + j;

    float h = 0.0f;
    if (tid < 256) ((_Float16*)hl)[tid] = (_Float16)0.0f;   // zero buffer 0
    __syncthreads();

    const int tstep = dir ? -1 : 1;
    int t = dir ? (NT - 1) : 0;

    // prefetch gx for the first step (q==0 threads only)
    _Float16 ngr = (_Float16)0.f, ngz = (_Float16)0.f, ngn = (_Float16)0.f;
    if (q == 0) {
        const _Float16* gxt = gxp + (size_t)t * G3;
        ngr = gxt[j]; ngz = gxt[256 + j]; ngn = gxt[512 + j];
    }

    int cur = 0;
    for (int tt = 0; tt < NT; ++tt, t += tstep) {
        // consume prefetched gx; issue next step's loads (latency hides under dots)
        float gxr = (float)ngr, gxz = (float)ngz, gxn = (float)ngn;
        if (q == 0 && tt + 1 < NT) {
            const _Float16* gxt = gxp + (size_t)(t + tstep) * G3;
            ngr = gxt[j]; ngz = gxt[256 + j]; ngn = gxt[512 + j];
        }

        // partial dots over this thread's 32 k2 values
        float ar = 0.f, az = 0.f, an = 0.f;
        const u32x4* hp = (const u32x4*)hl[cur] + q * 8;
        #pragma unroll
        for (int k4 = 0; k4 < 8; ++k4) {
            u32x4 hv = hp[k4];   // wave-uniform address -> LDS broadcast
            #pragma unroll
            for (int e = 0; e < 4; ++e) {
                int k = k4 * 4 + e;
                ar = fdot2f(hv[e], wr[k], ar);
                az = fdot2f(hv[e], wz[k], az);
                an = fdot2f(hv[e], wn[k], an);
            }
        }
        if (q != 0) {
            psum[q - 1][j]       = ar;
            psum[q - 1][256 + j] = az;
            psum[q - 1][512 + j] = an;
        }

        asm volatile("s_waitcnt lgkmcnt(0)" ::: "memory");
        __builtin_amdgcn_s_barrier();
        asm volatile("" ::: "memory");

        if (q == 0) {
            float arT = ar + psum[0][j]       + psum[1][j]       + psum[2][j];
            float azT = az + psum[0][256 + j] + psum[1][256 + j] + psum[2][256 + j];
            float anT = an + psum[0][512 + j] + psum[1][512 + j] + psum[2][512 + j];

            float r = sigmoidf_fast(gxr + arT);          // bhh_r folded into gxr
            float z = sigmoidf_fast(gxz + azT);          // bhh_z folded into gxz
            float n = tanhf_fast(gxn + r * (anT + bhn));
            h = z * h + (1.0f - z) * n;

            ((_Float16*)hl[cur ^ 1])[j] = (_Float16)h;
            outp[(size_t)t * 512] = h;
        }

        asm volatile("s_waitcnt lgkmcnt(0)" ::: "memory");
        __builtin_amdgcn_s_barrier();
        asm volatile("" ::: "memory");
        cur ^= 1;
    }

    if (q == 0) {
        float* hout = out + (size_t)NB * NT * 512 + dir * (NB * NH);
        hout[b * NH + j] = h;
    }
}

extern "C" void kernel_launch(void* const* d_in, const int* in_sizes, int n_in,
                              void* d_out, int out_size, void* d_ws, size_t ws_size,
                              hipStream_t stream) {
    const float* x      = (const float*)d_in[0];
    const float* wih_fw = (const float*)d_in[1];
    const float* whh_fw = (const float*)d_in[2];
    const float* bih_fw = (const float*)d_in[3];
    const float* bhh_fw = (const float*)d_in[4];
    const float* wih_bw = (const float*)d_in[5];
    const float* whh_bw = (const float*)d_in[6];
    const float* bih_bw = (const float*)d_in[7];
    const float* bhh_bw = (const float*)d_in[8];
    float* out = (float*)d_out;

    char* ws = (char*)d_ws;
    _Float16* gx = (_Float16*)ws;                      // 2*65536*768*2 = 201,326,592 B
    u32* wihp = (u32*)(ws + 201326592);                // 786,432 B
    u32* whhp = (u32*)(ws + 202113024);                // 786,432 B

    pack_w<<<768, 256, 0, stream>>>(wih_fw, wih_bw, wihp);
    pack_w<<<768, 256, 0, stream>>>(whh_fw, whh_bw, whhp);
    gemm_gx<<<dim3(4096, 2), 256, 0, stream>>>(x, wihp, bih_fw, bih_bw,
                                               bhh_fw, bhh_bw, gx);
    gru_rec<<<dim3(NB, 2), 1024, 0, stream>>>(gx, whhp, bhh_fw, bhh_bw, out);
}

// Round 7
// 1634.523 us; speedup vs baseline: 1.1391x; 1.0193x over previous
//
#include <hip/hip_runtime.h>
#include <hip/hip_fp16.h>

typedef unsigned int u32;
typedef _Float16 half2_t __attribute__((ext_vector_type(2)));
typedef u32 u32x4 __attribute__((ext_vector_type(4)));

// ---- constants (B=64, T=1024, D=H=256) ----
#define NB   64
#define NT   1024
#define NH   256
#define G3   768          // 3*H
#define NK2  128          // K/2 packed f16 pairs
#define WPACK_ELEMS 98304 // NK2 * G3 per direction
#define KPER   64         // k2 values per thread (NK2 / 2 wave-groups)

// Forbid rematerialization: value must live in a VGPR from here on.
#define PIN(x) asm volatile("" : "+v"(x))

static __device__ __forceinline__ float fdot2f(u32 a, u32 b, float c) {
#if __has_builtin(__builtin_amdgcn_fdot2)
    return __builtin_amdgcn_fdot2(__builtin_bit_cast(half2_t, a),
                                  __builtin_bit_cast(half2_t, b), c, false);
#else
    half2_t av = __builtin_bit_cast(half2_t, a);
    half2_t bv = __builtin_bit_cast(half2_t, b);
    c = fmaf((float)av[0], (float)bv[0], c);
    c = fmaf((float)av[1], (float)bv[1], c);
    return c;
#endif
}

static __device__ __forceinline__ u32 packh2(float lo, float hi) {
    half2_t v;
    v[0] = (_Float16)lo;
    v[1] = (_Float16)hi;
    return __builtin_bit_cast(u32, v);
}

static __device__ __forceinline__ float sigmoidf_fast(float x) {
    return 1.0f / (1.0f + __expf(-x));
}
static __device__ __forceinline__ float tanhf_fast(float x) {
    return 2.0f / (1.0f + __expf(-2.0f * x)) - 1.0f;
}

// Pack a (768,256) fp32 weight matrix (both directions) into f16-pair stream
// layout: dst[dir][k2][g] = half2(w[g][2k2], w[g][2k2+1]), g = gate*256 + j.
__global__ void pack_w(const float* __restrict__ src_fw,
                       const float* __restrict__ src_bw,
                       u32* __restrict__ dst) {
    int id = blockIdx.x * 256 + threadIdx.x;   // [0, 2*98304)
    int dir = id >= WPACK_ELEMS;
    int r   = id - dir * WPACK_ELEMS;          // [0, 98304)
    int j    = r & 255;
    int q    = r >> 8;                         // [0, 384)
    int gate = q % 3;
    int k2   = q / 3;
    const float* src = dir ? src_bw : src_fw;
    int g = gate * 256 + j;
    float lo = src[g * 256 + 2 * k2];
    float hi = src[g * 256 + 2 * k2 + 1];
    dst[dir * WPACK_ELEMS + k2 * G3 + g] = packh2(lo, hi);
}

// gates_x GEMM: gx[dir][m][g] = sum_k x[m][k]*w_ih[dir][g][k] + b_ih[dir][g]
// Also folds the ADDITIVE recurrent biases bhh_r, bhh_z into the r/z outputs
// (bhh_n cannot be folded: it is multiplied by the r gate in the recurrence).
__global__ __launch_bounds__(256) void gemm_gx(
        const float* __restrict__ x, const u32* __restrict__ wihp,
        const float* __restrict__ bih_fw, const float* __restrict__ bih_bw,
        const float* __restrict__ bhh_fw, const float* __restrict__ bhh_bw,
        _Float16* __restrict__ gx) {
    int dir = blockIdx.y;
    int m0  = blockIdx.x * 16;
    int j   = threadIdx.x;

    __shared__ u32 xs[16][NK2];
    #pragma unroll
    for (int rep = 0; rep < 8; ++rep) {
        int lin = rep * 256 + j;       // [0, 2048)
        int mi  = lin >> 7;
        int k2  = lin & 127;
        const float* xr = x + (size_t)(m0 + mi) * 256 + 2 * k2;
        xs[mi][k2] = packh2(xr[0], xr[1]);
    }
    __syncthreads();

    const u32* wp = wihp + dir * WPACK_ELEMS;
    const float* bih = dir ? bih_bw : bih_fw;
    const float* bhh = dir ? bhh_bw : bhh_fw;

    float accr[16], accz[16], accn[16];
    #pragma unroll
    for (int mi = 0; mi < 16; ++mi) { accr[mi] = 0.f; accz[mi] = 0.f; accn[mi] = 0.f; }

    #pragma unroll 2
    for (int k2 = 0; k2 < NK2; ++k2) {
        u32 wr = wp[k2 * G3 + j];
        u32 wz = wp[k2 * G3 + 256 + j];
        u32 wn = wp[k2 * G3 + 512 + j];
        #pragma unroll
        for (int mi = 0; mi < 16; ++mi) {
            u32 xv = xs[mi][k2];
            accr[mi] = fdot2f(xv, wr, accr[mi]);
            accz[mi] = fdot2f(xv, wz, accz[mi]);
            accn[mi] = fdot2f(xv, wn, accn[mi]);
        }
    }

    float br = bih[j] + bhh[j];                // fold bhh_r
    float bz = bih[256 + j] + bhh[256 + j];    // fold bhh_z
    float bn = bih[512 + j];
    _Float16* gxd = gx + (size_t)dir * 65536 * G3;
    #pragma unroll
    for (int mi = 0; mi < 16; ++mi) {
        size_t row = (size_t)(m0 + mi) * G3;
        gxd[row + j]       = (_Float16)(accr[mi] + br);
        gxd[row + 256 + j] = (_Float16)(accz[mi] + bz);
        gxd[row + 512 + j] = (_Float16)(accn[mi] + bn);
    }
}

// Recurrence: one block per (batch, direction) chain, 512 threads (8 waves).
// Thread (q = tid>>8 in {0,1}, j = tid&255) holds w_hh rows {j, 256+j, 512+j}
// for k2 in [64q, 64q+64) -> 192 weight VGPRs per thread.
//
// WHY 512 THREADS: a 1024-thread block forces 4 waves/SIMD -> hard cap 128
// regs/thread, which can NEVER hold 96 weights + working set (rounds 2-6
// all spilled). 8 waves -> 1 block/CU -> 2 waves/SIMD -> hard budget 256
// regs/thread; 192 weights + ~40 working fits with headroom.
//
// LDS OCCUPANCY CLAMP (non-DCE-able): 88 KB static LDS makes a second block
// per CU impossible, so the register allocator's achievable-occupancy bound
// is 2 waves/SIMD and its budget is the full 256 VGPRs. The pad is kept
// alive by a blockIdx-guarded store+load (grid.x=64, guard never true, but
// unprovable at compile time) -- round 6's pad was eliminated as dead.
__global__ __launch_bounds__(512)
void gru_rec(
        const _Float16* __restrict__ gx, const u32* __restrict__ whhp,
        const float* __restrict__ bhh_fw, const float* __restrict__ bhh_bw,
        float* __restrict__ out) {
    int b   = blockIdx.x;
    int dir = blockIdx.y;
    int tid = threadIdx.x;
    int j   = tid & 255;
    int q   = tid >> 8;          // wave-uniform: waves 0-3 -> 0, waves 4-7 -> 1

    __shared__ alignas(16) u32 hl[2][NK2];   // double-buffered h as packed f16 pairs
    __shared__ float psum[G3];               // partials from q=1 (3 KB)
    __shared__ u32 occ_pad[21504];           // 84 KB occupancy clamp (see above)
    if (blockIdx.x == 0x7FFFFFFFu) {         // never true at runtime; unprovable
        occ_pad[(tid * 21u) % 21504u] = tid;
        __syncthreads();
        out[tid] = (float)occ_pad[(tid * 7u) % 21504u];
    }

    const u32* wp = whhp + dir * WPACK_ELEMS;

    u32 wr[KPER], wz[KPER], wn[KPER];
    #pragma unroll
    for (int k = 0; k < KPER; ++k) {
        int k2 = q * KPER + k;
        wr[k] = wp[k2 * G3 + j];       PIN(wr[k]);
        wz[k] = wp[k2 * G3 + 256 + j]; PIN(wz[k]);
        wn[k] = wp[k2 * G3 + 512 + j]; PIN(wn[k]);
    }

    const float* bhh = dir ? bhh_bw : bhh_fw;
    float bhn = bhh[512 + j];    // bhh_r/bhh_z were folded into gx

    const _Float16* gxp = gx + ((size_t)dir * NB + b) * NT * G3;
    float* outp = out + (size_t)b * NT * 512 + dir * 256 + j;

    float h = 0.0f;
    if (tid < 256) ((_Float16*)hl)[tid] = (_Float16)0.0f;   // zero buffer 0
    __syncthreads();

    const int tstep = dir ? -1 : 1;
    int t = dir ? (NT - 1) : 0;

    // 2-deep gx prefetch ring (HBM latency ~900 cyc > one step's dot phase)
    _Float16 g0r = (_Float16)0.f, g0z = (_Float16)0.f, g0n = (_Float16)0.f;
    _Float16 g1r = (_Float16)0.f, g1z = (_Float16)0.f, g1n = (_Float16)0.f;
    if (q == 0) {
        const _Float16* gxt = gxp + (size_t)t * G3;
        g0r = gxt[j]; g0z = gxt[256 + j]; g0n = gxt[512 + j];
        const _Float16* gxt1 = gxp + (size_t)(t + tstep) * G3;
        g1r = gxt1[j]; g1z = gxt1[256 + j]; g1n = gxt1[512 + j];
    }

    int cur = 0;
    for (int tt = 0; tt < NT; ++tt, t += tstep) {
        float gxr = (float)g0r, gxz = (float)g0z, gxn = (float)g0n;
        g0r = g1r; g0z = g1z; g0n = g1n;
        if (q == 0 && tt + 2 < NT) {
            const _Float16* gxt = gxp + (size_t)(t + 2 * tstep) * G3;
            g1r = gxt[j]; g1z = gxt[256 + j]; g1n = gxt[512 + j];
        }

        // partial dots over this thread's 64 k2 values
        float ar = 0.f, az = 0.f, an = 0.f;
        const u32x4* hp = (const u32x4*)hl[cur] + q * 16;
        #pragma unroll
        for (int k4 = 0; k4 < 16; ++k4) {
            u32x4 hv = hp[k4];   // wave-uniform address -> LDS broadcast
            #pragma unroll
            for (int e = 0; e < 4; ++e) {
                int k = k4 * 4 + e;
                ar = fdot2f(hv[e], wr[k], ar);
                az = fdot2f(hv[e], wz[k], az);
                an = fdot2f(hv[e], wn[k], an);
            }
        }
        if (q != 0) {
            psum[j]       = ar;
            psum[256 + j] = az;
            psum[512 + j] = an;
        }

        asm volatile("s_waitcnt lgkmcnt(0)" ::: "memory");
        __builtin_amdgcn_s_barrier();
        asm volatile("" ::: "memory");

        if (q == 0) {
            float arT = ar + psum[j];
            float azT = az + psum[256 + j];
            float anT = an + psum[512 + j];

            float r = sigmoidf_fast(gxr + arT);          // bhh_r folded into gxr
            float z = sigmoidf_fast(gxz + azT);          // bhh_z folded into gxz
            float n = tanhf_fast(gxn + r * (anT + bhn));
            h = z * h + (1.0f - z) * n;

            ((_Float16*)hl[cur ^ 1])[j] = (_Float16)h;
            outp[(size_t)t * 512] = h;
        }

        asm volatile("s_waitcnt lgkmcnt(0)" ::: "memory");
        __builtin_amdgcn_s_barrier();
        asm volatile("" ::: "memory");
        cur ^= 1;
    }

    if (q == 0) {
        float* hout = out + (size_t)NB * NT * 512 + dir * (NB * NH);
        hout[b * NH + j] = h;
    }
}

extern "C" void kernel_launch(void* const* d_in, const int* in_sizes, int n_in,
                              void* d_out, int out_size, void* d_ws, size_t ws_size,
                              hipStream_t stream) {
    const float* x      = (const float*)d_in[0];
    const float* wih_fw = (const float*)d_in[1];
    const float* whh_fw = (const float*)d_in[2];
    const float* bih_fw = (const float*)d_in[3];
    const float* bhh_fw = (const float*)d_in[4];
    const float* wih_bw = (const float*)d_in[5];
    const float* whh_bw = (const float*)d_in[6];
    const float* bih_bw = (const float*)d_in[7];
    const float* bhh_bw = (const float*)d_in[8];
    float* out = (float*)d_out;

    char* ws = (char*)d_ws;
    _Float16* gx = (_Float16*)ws;                      // 2*65536*768*2 = 201,326,592 B
    u32* wihp = (u32*)(ws + 201326592);                // 786,432 B
    u32* whhp = (u32*)(ws + 202113024);                // 786,432 B

    pack_w<<<768, 256, 0, stream>>>(wih_fw, wih_bw, wihp);
    pack_w<<<768, 256, 0, stream>>>(whh_fw, whh_bw, whhp);
    gemm_gx<<<dim3(4096, 2), 256, 0, stream>>>(x, wihp, bih_fw, bih_bw,
                                               bhh_fw, bhh_bw, gx);
    gru_rec<<<dim3(NB, 2), 512, 0, stream>>>(gx, whhp, bhh_fw, bhh_bw, out);
}

// Round 8
// 1627.883 us; speedup vs baseline: 1.1437x; 1.0041x over previous
//
#include <hip/hip_runtime.h>
#include <hip/hip_fp16.h>

typedef unsigned int u32;
typedef _Float16 half2_t __attribute__((ext_vector_type(2)));
typedef u32 u32x4 __attribute__((ext_vector_type(4)));

// ---- constants (B=64, T=1024, D=H=256) ----
#define NB   64
#define NT   1024
#define NH   256
#define G3   768          // 3*H
#define NK2  128          // K/2 packed f16 pairs
#define WPACK_ELEMS 98304 // NK2 * G3 per direction
#define KPER   64         // k2 values per thread (NK2 / 2 wave-groups)

// Forbid rematerialization: value must live in a VGPR from here on.
#define PIN(x) asm volatile("" : "+v"(x))

static __device__ __forceinline__ float fdot2f(u32 a, u32 b, float c) {
#if __has_builtin(__builtin_amdgcn_fdot2)
    return __builtin_amdgcn_fdot2(__builtin_bit_cast(half2_t, a),
                                  __builtin_bit_cast(half2_t, b), c, false);
#else
    half2_t av = __builtin_bit_cast(half2_t, a);
    half2_t bv = __builtin_bit_cast(half2_t, b);
    c = fmaf((float)av[0], (float)bv[0], c);
    c = fmaf((float)av[1], (float)bv[1], c);
    return c;
#endif
}

static __device__ __forceinline__ u32 packh2(float lo, float hi) {
    half2_t v;
    v[0] = (_Float16)lo;
    v[1] = (_Float16)hi;
    return __builtin_bit_cast(u32, v);
}

static __device__ __forceinline__ float sigmoidf_fast(float x) {
    return 1.0f / (1.0f + __expf(-x));
}
static __device__ __forceinline__ float tanhf_fast(float x) {
    return 2.0f / (1.0f + __expf(-2.0f * x)) - 1.0f;
}

// Pack a (768,256) fp32 weight matrix (both directions) into f16-pair stream
// layout: dst[dir][k2][g] = half2(w[g][2k2], w[g][2k2+1]), g = gate*256 + j.
__global__ void pack_w(const float* __restrict__ src_fw,
                       const float* __restrict__ src_bw,
                       u32* __restrict__ dst) {
    int id = blockIdx.x * 256 + threadIdx.x;   // [0, 2*98304)
    int dir = id >= WPACK_ELEMS;
    int r   = id - dir * WPACK_ELEMS;          // [0, 98304)
    int j    = r & 255;
    int q    = r >> 8;                         // [0, 384)
    int gate = q % 3;
    int k2   = q / 3;
    const float* src = dir ? src_bw : src_fw;
    int g = gate * 256 + j;
    float lo = src[g * 256 + 2 * k2];
    float hi = src[g * 256 + 2 * k2 + 1];
    dst[dir * WPACK_ELEMS + k2 * G3 + g] = packh2(lo, hi);
}

// gates_x GEMM: gx[dir][m][g] = sum_k x[m][k]*w_ih[dir][g][k] + b_ih[dir][g]
// Also folds the ADDITIVE recurrent biases bhh_r, bhh_z into the r/z outputs
// (bhh_n cannot be folded: it is multiplied by the r gate in the recurrence).
__global__ __launch_bounds__(256) void gemm_gx(
        const float* __restrict__ x, const u32* __restrict__ wihp,
        const float* __restrict__ bih_fw, const float* __restrict__ bih_bw,
        const float* __restrict__ bhh_fw, const float* __restrict__ bhh_bw,
        _Float16* __restrict__ gx) {
    int dir = blockIdx.y;
    int m0  = blockIdx.x * 16;
    int j   = threadIdx.x;

    __shared__ u32 xs[16][NK2];
    #pragma unroll
    for (int rep = 0; rep < 8; ++rep) {
        int lin = rep * 256 + j;       // [0, 2048)
        int mi  = lin >> 7;
        int k2  = lin & 127;
        const float* xr = x + (size_t)(m0 + mi) * 256 + 2 * k2;
        xs[mi][k2] = packh2(xr[0], xr[1]);
    }
    __syncthreads();

    const u32* wp = wihp + dir * WPACK_ELEMS;
    const float* bih = dir ? bih_bw : bih_fw;
    const float* bhh = dir ? bhh_bw : bhh_fw;

    float accr[16], accz[16], accn[16];
    #pragma unroll
    for (int mi = 0; mi < 16; ++mi) { accr[mi] = 0.f; accz[mi] = 0.f; accn[mi] = 0.f; }

    #pragma unroll 2
    for (int k2 = 0; k2 < NK2; ++k2) {
        u32 wr = wp[k2 * G3 + j];
        u32 wz = wp[k2 * G3 + 256 + j];
        u32 wn = wp[k2 * G3 + 512 + j];
        #pragma unroll
        for (int mi = 0; mi < 16; ++mi) {
            u32 xv = xs[mi][k2];
            accr[mi] = fdot2f(xv, wr, accr[mi]);
            accz[mi] = fdot2f(xv, wz, accz[mi]);
            accn[mi] = fdot2f(xv, wn, accn[mi]);
        }
    }

    float br = bih[j] + bhh[j];                // fold bhh_r
    float bz = bih[256 + j] + bhh[256 + j];    // fold bhh_z
    float bn = bih[512 + j];
    _Float16* gxd = gx + (size_t)dir * 65536 * G3;
    #pragma unroll
    for (int mi = 0; mi < 16; ++mi) {
        size_t row = (size_t)(m0 + mi) * G3;
        gxd[row + j]       = (_Float16)(accr[mi] + br);
        gxd[row + 256 + j] = (_Float16)(accz[mi] + bz);
        gxd[row + 512 + j] = (_Float16)(accn[mi] + bn);
    }
}

// Recurrence: one block per (batch, direction) chain, 512 threads (8 waves).
// Thread (q = tid>>8 in {0,1}, j = tid&255) holds w_hh rows {j, 256+j, 512+j}
// for k2 in [64q, 64q+64) -> 192 weight VGPRs per thread.
//
// REGISTER-BUDGET FIX (rounds 2-7 post-mortems): the allocator's VGPR budget
// tracks MIN waves-per-EU, which floors at 4 (budget 128) regardless of the
// LDS-limited achievable occupancy -- r7 proved this (LDS clamp landed, 1
// block/CU, yet VGPR capped at 120 with spills). amdgpu_waves_per_eu(2,2)
// lowers the floor explicitly: budget = 512/2 = 256 regs/thread. Live set
// 192 weights + ~40 working = ~232 <= 256, so a no-spill assignment exists.
// The LDS clamp below keeps 2 waves/EU the PROVABLE max so (2,2) is
// consistent; PIN() keeps the loads from being sunk back into the loop.
__global__ __launch_bounds__(512)
__attribute__((amdgpu_waves_per_eu(2, 2)))
void gru_rec(
        const _Float16* __restrict__ gx, const u32* __restrict__ whhp,
        const float* __restrict__ bhh_fw, const float* __restrict__ bhh_bw,
        float* __restrict__ out) {
    int b   = blockIdx.x;
    int dir = blockIdx.y;
    int tid = threadIdx.x;
    int j   = tid & 255;
    int q   = tid >> 8;          // wave-uniform: waves 0-3 -> 0, waves 4-7 -> 1

    __shared__ alignas(16) u32 hl[2][NK2];   // double-buffered h as packed f16 pairs
    __shared__ float psum[G3];               // partials from q=1 (3 KB)
    __shared__ u32 occ_pad[21504];           // 84 KB occupancy clamp (see above)
    if (blockIdx.x == 0x7FFFFFFFu) {         // never true at runtime; unprovable
        occ_pad[(tid * 21u) % 21504u] = tid;
        __syncthreads();
        out[tid] = (float)occ_pad[(tid * 7u) % 21504u];
    }

    const u32* wp = whhp + dir * WPACK_ELEMS;

    u32 wr[KPER], wz[KPER], wn[KPER];
    #pragma unroll
    for (int k = 0; k < KPER; ++k) {
        int k2 = q * KPER + k;
        wr[k] = wp[k2 * G3 + j];       PIN(wr[k]);
        wz[k] = wp[k2 * G3 + 256 + j]; PIN(wz[k]);
        wn[k] = wp[k2 * G3 + 512 + j]; PIN(wn[k]);
    }

    const float* bhh = dir ? bhh_bw : bhh_fw;
    float bhn = bhh[512 + j];    // bhh_r/bhh_z were folded into gx

    const _Float16* gxp = gx + ((size_t)dir * NB + b) * NT * G3;
    float* outp = out + (size_t)b * NT * 512 + dir * 256 + j;

    float h = 0.0f;
    if (tid < 256) ((_Float16*)hl)[tid] = (_Float16)0.0f;   // zero buffer 0
    __syncthreads();

    const int tstep = dir ? -1 : 1;
    int t = dir ? (NT - 1) : 0;

    // 2-deep gx prefetch ring (HBM latency ~900 cyc > one step's dot phase)
    _Float16 g0r = (_Float16)0.f, g0z = (_Float16)0.f, g0n = (_Float16)0.f;
    _Float16 g1r = (_Float16)0.f, g1z = (_Float16)0.f, g1n = (_Float16)0.f;
    if (q == 0) {
        const _Float16* gxt = gxp + (size_t)t * G3;
        g0r = gxt[j]; g0z = gxt[256 + j]; g0n = gxt[512 + j];
        const _Float16* gxt1 = gxp + (size_t)(t + tstep) * G3;
        g1r = gxt1[j]; g1z = gxt1[256 + j]; g1n = gxt1[512 + j];
    }

    int cur = 0;
    for (int tt = 0; tt < NT; ++tt, t += tstep) {
        float gxr = (float)g0r, gxz = (float)g0z, gxn = (float)g0n;
        g0r = g1r; g0z = g1z; g0n = g1n;
        if (q == 0 && tt + 2 < NT) {
            const _Float16* gxt = gxp + (size_t)(t + 2 * tstep) * G3;
            g1r = gxt[j]; g1z = gxt[256 + j]; g1n = gxt[512 + j];
        }

        // partial dots over this thread's 64 k2 values
        float ar = 0.f, az = 0.f, an = 0.f;
        const u32x4* hp = (const u32x4*)hl[cur] + q * 16;
        #pragma unroll
        for (int k4 = 0; k4 < 16; ++k4) {
            u32x4 hv = hp[k4];   // wave-uniform address -> LDS broadcast
            #pragma unroll
            for (int e = 0; e < 4; ++e) {
                int k = k4 * 4 + e;
                ar = fdot2f(hv[e], wr[k], ar);
                az = fdot2f(hv[e], wz[k], az);
                an = fdot2f(hv[e], wn[k], an);
            }
        }
        if (q != 0) {
            psum[j]       = ar;
            psum[256 + j] = az;
            psum[512 + j] = an;
        }

        asm volatile("s_waitcnt lgkmcnt(0)" ::: "memory");
        __builtin_amdgcn_s_barrier();
        asm volatile("" ::: "memory");

        if (q == 0) {
            float arT = ar + psum[j];
            float azT = az + psum[256 + j];
            float anT = an + psum[512 + j];

            float r = sigmoidf_fast(gxr + arT);          // bhh_r folded into gxr
            float z = sigmoidf_fast(gxz + azT);          // bhh_z folded into gxz
            float n = tanhf_fast(gxn + r * (anT + bhn));
            h = z * h + (1.0f - z) * n;

            ((_Float16*)hl[cur ^ 1])[j] = (_Float16)h;
            outp[(size_t)t * 512] = h;
        }

        asm volatile("s_waitcnt lgkmcnt(0)" ::: "memory");
        __builtin_amdgcn_s_barrier();
        asm volatile("" ::: "memory");
        cur ^= 1;
    }

    if (q == 0) {
        float* hout = out + (size_t)NB * NT * 512 + dir * (NB * NH);
        hout[b * NH + j] = h;
    }
}

extern "C" void kernel_launch(void* const* d_in, const int* in_sizes, int n_in,
                              void* d_out, int out_size, void* d_ws, size_t ws_size,
                              hipStream_t stream) {
    const float* x      = (const float*)d_in[0];
    const float* wih_fw = (const float*)d_in[1];
    const float* whh_fw = (const float*)d_in[2];
    const float* bih_fw = (const float*)d_in[3];
    const float* bhh_fw = (const float*)d_in[4];
    const float* wih_bw = (const float*)d_in[5];
    const float* whh_bw = (const float*)d_in[6];
    const float* bih_bw = (const float*)d_in[7];
    const float* bhh_bw = (const float*)d_in[8];
    float* out = (float*)d_out;

    char* ws = (char*)d_ws;
    _Float16* gx = (_Float16*)ws;                      // 2*65536*768*2 = 201,326,592 B
    u32* wihp = (u32*)(ws + 201326592);                // 786,432 B
    u32* whhp = (u32*)(ws + 202113024);                // 786,432 B

    pack_w<<<768, 256, 0, stream>>>(wih_fw, wih_bw, wihp);
    pack_w<<<768, 256, 0, stream>>>(whh_fw, whh_bw, whhp);
    gemm_gx<<<dim3(4096, 2), 256, 0, stream>>>(x, wihp, bih_fw, bih_bw,
                                               bhh_fw, bhh_bw, gx);
    gru_rec<<<dim3(NB, 2), 512, 0, stream>>>(gx, whhp, bhh_fw, bhh_bw, out);
}